// Round 7
// baseline (126.672 us; speedup 1.0000x reference)
//
#include <hip/hip_runtime.h>
#include <hip/hip_bf16.h>
#include <hip/hip_fp16.h>
#include <math.h>

#define BB 4
#define CC 192
#define HH 56
#define WW 56
#define HWW 3136

typedef __attribute__((ext_vector_type(8))) short short8;
typedef __attribute__((ext_vector_type(8))) _Float16 half8;
typedef __attribute__((ext_vector_type(4))) float f32x4;

__device__ __forceinline__ unsigned short f2b(float f) {
    __hip_bfloat16 h = __float2bfloat16(f);
    return __builtin_bit_cast(unsigned short, h);
}
__device__ __forceinline__ float b2f(unsigned short u) {
    unsigned int x = ((unsigned int)u) << 16;
    return __builtin_bit_cast(float, x);
}
__device__ __forceinline__ unsigned short f2h(float f) {
    __half h = __float2half_rn(f);
    return __builtin_bit_cast(unsigned short, h);
}
__device__ __forceinline__ float2 h2f2(unsigned int u) {
    return __half22float2(__builtin_bit_cast(__half2, u));
}

// ---------------------------------------------------------------------------
// Kernel 1: blocks [0,2352): transpose x (B,C,H,W) -> split-bf16 xth/xtl (for
//           scores) + fp16 xh16 (for GEMM), all (B,HW,C).
//           blocks [2352,2640): W' = [C1;C2] -> fp16 wh16 (N=384, K=192)
// ---------------------------------------------------------------------------
__global__ __launch_bounds__(256) void k_pre(const float* __restrict__ x,
                                             const float* __restrict__ cw,
                                             unsigned short* __restrict__ xth,
                                             unsigned short* __restrict__ xtl,
                                             unsigned short* __restrict__ xh16,
                                             unsigned short* __restrict__ wh16) {
    int tid = threadIdx.x, bid = blockIdx.x;
    if (bid < 2352) {
        __shared__ float tile[32][33];
        int b = bid / 588, rem = bid % 588;
        int by = rem / 98, bx = rem % 98;
        int tx = tid & 31, ty = tid >> 5;
        int p0 = bx * 32, c0 = by * 32;
#pragma unroll
        for (int i = 0; i < 4; i++) {
            int c = c0 + ty + 8 * i;
            tile[ty + 8 * i][tx] = x[(b * CC + c) * HWW + p0 + tx];
        }
        __syncthreads();
#pragma unroll
        for (int i = 0; i < 4; i++) {
            int p = p0 + ty + 8 * i;
            float v = tile[tx][ty + 8 * i];
            unsigned short hi = f2b(v);
            size_t o = (size_t)(b * HWW + p) * CC + c0 + tx;
            xth[o] = hi;
            xtl[o] = f2b(v - b2f(hi));
            xh16[o] = f2h(v);
        }
    } else {
        int i = (bid - 2352) * 256 + tid;     // 288*256 = 73728 = 384*192 exact
        if (i < 384 * 192) {
            int n = i / 192, k = i % 192;
            float v = (n < 192) ? cw[n * 384 + k] : cw[(n - 192) * 384 + 192 + k];
            wh16[i] = f2h(v);
        }
    }
}

// ---------------------------------------------------------------------------
// Kernel 2 (fused independent work):
//   blocks [0,1792):    scores (pair symmetry, split-bf16 recon) -> sp
//   blocks [1792,2968): GEMM [u|z] = W'·x^T, M=12544, N=384, K=192, fp16
//                       single-MFMA (16x16x32_f16), LDS 18.4KB -> 8 blk/CU.
// ---------------------------------------------------------------------------
__global__ __launch_bounds__(256) void k_mid(const unsigned short* __restrict__ xth,
                                             const unsigned short* __restrict__ xtl,
                                             const unsigned short* __restrict__ xh16,
                                             const unsigned short* __restrict__ wh16,
                                             float* __restrict__ sp,
                                             float* __restrict__ u,
                                             float* __restrict__ z) {
    __shared__ __align__(16) char smem[18432];
    int tid = threadIdx.x, bid = blockIdx.x;

    if (bid < 1792) {                 // ---------------- scores ----------------
        float* Xs = (float*)smem;     // 28 rows x 96ch (+4 pad) -- 11.2KB
        const float K2 = 0.38490017945975050f;  // 2/sqrt(27)
        bool isH = bid < 896;
        int lid = isH ? bid : bid - 896;
        int half = lid & 1;
        int rp = (lid >> 1) & 1;
        int cb2 = lid >> 2;
        int b = cb2 / 56, l0 = cb2 % 56;
        int r0 = rp * 2;

        const unsigned short* srch = xth + (size_t)(b * HWW) * CC + half * 96;
        const unsigned short* srcl = xtl + (size_t)(b * HWW) * CC + half * 96;
        for (int idx = tid; idx < 28 * 12; idx += 256) {
            int t2 = idx / 12, cq = idx % 12;
            int pi = (r0 + t2 / 14) + 4 * (t2 % 14);
            int pix = isH ? (pi * WW + l0) : (l0 * WW + pi);
            short8 h8 = *(const short8*)(srch + (size_t)pix * CC + cq * 8);
            short8 l8 = *(const short8*)(srcl + (size_t)pix * CC + cq * 8);
            float o[8];
#pragma unroll
            for (int e = 0; e < 8; e++)
                o[e] = b2f((unsigned short)h8[e]) + b2f((unsigned short)l8[e]);
            *(float4*)&Xs[t2 * 100 + cq * 8] = *(float4*)&o[0];
            *(float4*)&Xs[t2 * 100 + cq * 8 + 4] = *(float4*)&o[4];
        }
        __syncthreads();

        int perCls = isH ? 105 : 91;
        if (tid < 2 * perCls) {
            int cls = tid / perCls, p = tid % perCls;
            int a, bb;
            if (isH) {
                a = (int)((sqrtf((float)(8 * p + 1)) - 1.0f) * 0.5f);
                bb = p - (a * (a + 1)) / 2;
            } else {
                int ap = (int)((sqrtf((float)(8 * p + 1)) - 1.0f) * 0.5f);
                bb = p - (ap * (ap + 1)) / 2;
                a = ap + 1;
            }
            const float* pA = &Xs[(cls * 14 + a) * 100];
            const float* pB = &Xs[(cls * 14 + bb) * 100];
            float s0 = 0.f, s1 = 0.f, s2 = 0.f, s3 = 0.f;
#pragma unroll
            for (int q = 0; q < 24; q++) {
                float4 av = *(const float4*)(pA + q * 4);
                float4 bv = *(const float4*)(pB + q * 4);
                s0 += __builtin_amdgcn_rcpf(__expf(av.x * bv.x * K2) + 1.0f);
                s1 += __builtin_amdgcn_rcpf(__expf(av.y * bv.y * K2) + 1.0f);
                s2 += __builtin_amdgcn_rcpf(__expf(av.z * bv.z * K2) + 1.0f);
                s3 += __builtin_amdgcn_rcpf(__expf(av.w * bv.w * K2) + 1.0f);
            }
            float s = 96.0f - 2.0f * (s0 + s1 + s2 + s3);   // sum_c tanh
            int r = r0 + cls;
            size_t base = (size_t)(half * BB + b) * HWW;
            if (isH) {
                int i1 = a - bb;
                int h1 = r + 4 * a, h2 = r + 4 * bb;
                sp[(base + h1 * WW + l0) * 32 + i1] = s;
                if (a != bb) sp[(base + h2 * WW + l0) * 32 + (14 - i1)] = s;
            } else {
                int d = a - bb;                        // 1..13
                int w1 = r + 4 * a, w2 = r + 4 * bb;
                sp[(base + l0 * WW + w1) * 32 + 14 + (d - 1)] = s;
                sp[(base + l0 * WW + w2) * 32 + 14 + (13 - d)] = s;
            }
        }
        return;
    }

    // ---------------- GEMM [u|z], fp16, tile 64x64, K=192 ----------------
    {
        unsigned short* Ah = (unsigned short*)smem;   // [64][72]
        unsigned short* Bh = Ah + 64 * 72;            // [64][72]
        float* Ds = (float*)smem;                     // reused for epilogue
        int vb = bid - 1792;                  // 0..1175
        int bm = (vb % 196) * 64, bn = (vb / 196) * 64;
        int lane = tid & 63, wv = tid >> 6;

        f32x4 acc[4] = {{0,0,0,0},{0,0,0,0},{0,0,0,0},{0,0,0,0}};

        for (int kc = 0; kc < 3; kc++) {
#pragma unroll
            for (int r2 = 0; r2 < 2; r2++) {
                int idx = tid + r2 * 256;
                int m = idx >> 3, kq = idx & 7;
                size_t ao = (size_t)(bm + m) * CC + kc * 64 + kq * 8;
                *(short8*)&Ah[m * 72 + kq * 8] = *(const short8*)(xh16 + ao);
                size_t bo = (size_t)(bn + m) * 192 + kc * 64 + kq * 8;
                *(short8*)&Bh[m * 72 + kq * 8] = *(const short8*)(wh16 + bo);
            }
            __syncthreads();
            int n0 = wv * 16;
            int k8 = lane >> 4;
            int col = lane & 15;
#pragma unroll
            for (int ks = 0; ks < 64; ks += 32) {
                int koff = ks + k8 * 8;
                half8 bf = *(const half8*)&Bh[(n0 + col) * 72 + koff];
#pragma unroll
                for (int fm = 0; fm < 4; fm++) {
                    half8 af = *(const half8*)&Ah[(fm * 16 + col) * 72 + koff];
                    acc[fm] = __builtin_amdgcn_mfma_f32_16x16x32_f16(af, bf, acc[fm], 0, 0, 0);
                }
            }
            __syncthreads();
        }
        // LDS transpose: Ds[m][n], stride 68
        {
            int col = lane & 15, rowq = lane >> 4;
#pragma unroll
            for (int fm = 0; fm < 4; fm++)
#pragma unroll
                for (int rg = 0; rg < 4; rg++)
                    Ds[(fm * 16 + rowq * 4 + rg) * 68 + wv * 16 + col] = acc[fm][rg];
        }
        __syncthreads();
        // Store pixel-major: u (n<192) or z (n>=192)
        {
            int c4 = tid & 15, m0 = tid >> 4;
            int cg = bn + c4 * 4;
            float* dst = (cg < 192) ? u : z;
            int cc = (cg < 192) ? cg : cg - 192;
#pragma unroll
            for (int p = 0; p < 4; p++) {
                int m = m0 + p * 16;
                float4 v = *(float4*)&Ds[m * 68 + c4 * 4];
                *(float4*)&dst[(size_t)(bm + m) * CC + cc] = v;
            }
        }
    }
}

// ---------------------------------------------------------------------------
// Kernel 3: per-pixel softmax over 27 scores -> f16 weights wn16[pix][32]
// (slots 27..31 = 0). 49 blocks x 256 threads = 12544 pixels exactly.
// ---------------------------------------------------------------------------
__global__ __launch_bounds__(256) void k_soft(const float* __restrict__ sp,
                                              unsigned short* __restrict__ wn16) {
    int gp = blockIdx.x * 256 + threadIdx.x;           // b*3136 + pix
    const float4* p0 = (const float4*)&sp[(size_t)gp * 32];
    const float4* p1 = (const float4*)&sp[((size_t)(4 * HWW) + gp) * 32];
    float sc[28];
#pragma unroll
    for (int j = 0; j < 7; j++) {
        float4 a = p0[j], v = p1[j];
        sc[4 * j + 0] = a.x + v.x; sc[4 * j + 1] = a.y + v.y;
        sc[4 * j + 2] = a.z + v.z; sc[4 * j + 3] = a.w + v.w;
    }
    float mx = -1e30f;
#pragma unroll
    for (int s = 0; s < 27; s++) mx = fmaxf(mx, sc[s]);
    float sum = 0.f;
#pragma unroll
    for (int s = 0; s < 27; s++) { sc[s] = __expf(sc[s] - mx); sum += sc[s]; }
    float inv = __builtin_amdgcn_rcpf(sum);

    unsigned short hw[32];
#pragma unroll
    for (int s = 0; s < 27; s++) hw[s] = f2h(sc[s] * inv);
#pragma unroll
    for (int s = 27; s < 32; s++) hw[s] = 0;
    unsigned short* dst = wn16 + (size_t)gp * 32;
#pragma unroll
    for (int q = 0; q < 4; q++)
        *(short8*)(dst + q * 8) = *(short8*)&hw[q * 8];
}

// ---------------------------------------------------------------------------
// Kernel 4: fused H+W accumulation + bias + BN + GELU.
// Block = (b, r-phase, 8-ch chunk, t-half). LDS: z slab (25KB) + this block's
// 392-pixel f16 weight slab (28KB, stride 36 -> conflict-free h2-reads).
// Grid 768 = 4b x 4r x 24cc x 2th, 448 threads (tid = w*8+c).
// ---------------------------------------------------------------------------
__global__ __launch_bounds__(448, 1) void k_tail(const float* __restrict__ u,
                                                 const float* __restrict__ z,
                                                 const unsigned short* __restrict__ wn16,
                                                 const float* __restrict__ cb,
                                                 const float* __restrict__ gma,
                                                 const float* __restrict__ bta,
                                                 const float* __restrict__ mea,
                                                 const float* __restrict__ var,
                                                 float* __restrict__ y) {
    __shared__ float Zs[14 * 56 * 8];            // 25088 B, [t][w][c]
    __shared__ unsigned short W16[7 * 56 * 36];  // 28224 B, [tq][w][36] (pad)
    int tid = threadIdx.x, bid = blockIdx.x;
    int th = bid & 1;
    int t1 = bid >> 1;                    // 0..383
    int cc = t1 % 24;
    int t2 = t1 / 24;                     // 0..15
    int r = t2 & 3;
    int b = t2 >> 2;
    int w = tid >> 3, c = tid & 7;
    int cg = cc * 8 + c;
    int hbase = r + 4 * (th * 7);

    // stage z slab: rows r, r+4, ..., r+52 (all 14 t); channels [cc*8, cc*8+8)
#pragma unroll
    for (int it = 0; it < 2; it++) {
        int idx = tid + it * 448;
        if (idx < 784) {
            int t = idx / 56, ww = idx - t * 56;
            const float* s = z + ((size_t)(b * HWW + (r + 4 * t) * WW + ww)) * CC + cc * 8;
            float4 v0 = *(const float4*)s;
            float4 v1 = *(const float4*)(s + 4);
            float* d = &Zs[(t * 56 + ww) * 8];
            *(float4*)d = v0;
            *(float4*)(d + 4) = v1;
        }
    }
    // stage weight slab: 392 pixels x 32 halves (64B each), 16B chunks
    for (int i = tid; i < 392 * 4; i += 448) {
        int pl = i >> 2, q = i & 3;
        int tq = pl / 56, ww = pl - tq * 56;
        int row = hbase + 4 * tq;
        size_t gsrc = ((size_t)(b * HWW + row * WW + ww)) * 32 + q * 8;
        short8 v = *(const short8*)(wn16 + gsrc);
        *(short8*)&W16[(tq * 56 + ww) * 36 + q * 8] = v;
    }
    __syncthreads();

    // this thread's z column, pre-rotated by th*7 so all reg indices are static
    float zc[14];
#pragma unroll
    for (int m = 0; m < 14; m++) {
        int t0 = m + th * 7;
        if (t0 >= 14) t0 -= 14;
        zc[m] = Zs[(t0 * 56 + w) * 8 + c];
    }

    float bias = cb[cg];
    float ginv = gma[cg] * rsqrtf(var[cg] + 1e-5f);
    float bt = bta[cg];
    float me = mea[cg];

    float acc0[7];
#pragma unroll
    for (int tt = 0; tt < 7; tt++) {
        int pix = (hbase + 4 * tt) * WW + w;
        acc0[tt] = u[((size_t)(b * HWW + pix)) * CC + cg];
    }

#pragma unroll
    for (int tt = 0; tt < 7; tt++) {
        int t = th * 7 + tt;
        int pix = (hbase + 4 * tt) * WW + w;
        int pb = (tt * 56 + w) * 36;
        float a = acc0[tt];

        // H-part: halves 0..13 = wt[i], zc rotated so indices are static
#pragma unroll
        for (int p = 0; p < 7; p++) {
            float2 f2 = h2f2(*(const unsigned int*)&W16[pb + 2 * p]);
            a += f2.x * zc[(tt - 2 * p + 28) % 14];
            a += f2.y * zc[(tt - 2 * p - 1 + 28) % 14];
        }
        // W-part: halves 14..26 = wt[13+j] (j=1..13); half 27 = 0 pad
#pragma unroll
        for (int p = 7; p < 14; p++) {
            float2 f2 = h2f2(*(const unsigned int*)&W16[pb + 2 * p]);
            int j0 = 2 * p - 13, j1 = 2 * p - 12;
            int wj0 = w - 4 * j0; if (wj0 < 0) wj0 += 56;
            int wj1 = w - 4 * j1; if (wj1 < 0) wj1 += 56;
            a += f2.x * Zs[(t * 56 + wj0) * 8 + c];
            a += f2.y * Zs[(t * 56 + wj1) * 8 + c];
        }

        float v = (a + bias - me) * ginv + bt;
        v = 0.5f * v * (1.0f + erff(v * 0.70710678118654752f));
        y[((size_t)(b * CC + cg)) * HWW + pix] = v;
    }
}

// ---------------------------------------------------------------------------
extern "C" void kernel_launch(void* const* d_in, const int* in_sizes, int n_in,
                              void* d_out, int out_size, void* d_ws, size_t ws_size,
                              hipStream_t stream) {
    const float* x   = (const float*)d_in[0];
    const float* cw  = (const float*)d_in[1];
    const float* cb  = (const float*)d_in[2];
    const float* gma = (const float*)d_in[3];
    const float* bta = (const float*)d_in[4];
    const float* mea = (const float*)d_in[5];
    const float* var = (const float*)d_in[6];
    float* out = (float*)d_out;

    float* ws = (float*)d_ws;
    float*          sp   = ws;                                  //   802,816 f
    float*          u    = ws + 802816;                         // 2,408,448 f
    float*          z    = ws + 3211264;                        // 2,408,448 f
    unsigned short* xth  = (unsigned short*)(ws + 5619712);     // 2,408,448 us
    unsigned short* xtl  = (unsigned short*)(ws + 6823936);     // 2,408,448 us
    unsigned short* xh16 = (unsigned short*)(ws + 8028160);     // 2,408,448 us -> ends 9,232,384
    unsigned short* wh16 = (unsigned short*)(ws + 9232384);     //    73,728 us -> ends 9,269,248
    unsigned short* wn16 = (unsigned short*)(ws + 9269248);     //   401,408 us

    k_pre<<<2640, 256, 0, stream>>>(x, cw, xth, xtl, xh16, wh16);
    k_mid<<<2968, 256, 0, stream>>>(xth, xtl, xh16, wh16, sp, u, z);
    k_soft<<<49, 256, 0, stream>>>(sp, wn16);
    k_tail<<<768, 448, 0, stream>>>(u, z, wn16, cb, gma, bta, mea, var, out);
}

// Round 8
// 125.827 us; speedup vs baseline: 1.0067x; 1.0067x over previous
//
#include <hip/hip_runtime.h>
#include <hip/hip_bf16.h>
#include <hip/hip_fp16.h>
#include <math.h>

#define BB 4
#define CC 192
#define HH 56
#define WW 56
#define HWW 3136

typedef __attribute__((ext_vector_type(8))) short short8;
typedef __attribute__((ext_vector_type(4))) short short4v;
typedef __attribute__((ext_vector_type(8))) _Float16 half8;
typedef __attribute__((ext_vector_type(4))) float f32x4;

__device__ __forceinline__ unsigned short f2b(float f) {
    __hip_bfloat16 h = __float2bfloat16(f);
    return __builtin_bit_cast(unsigned short, h);
}
__device__ __forceinline__ float b2f(unsigned short u) {
    unsigned int x = ((unsigned int)u) << 16;
    return __builtin_bit_cast(float, x);
}
__device__ __forceinline__ unsigned short f2h(float f) {
    __half h = __float2half_rn(f);
    return __builtin_bit_cast(unsigned short, h);
}
__device__ __forceinline__ float2 h2f2(unsigned int u) {
    return __half22float2(__builtin_bit_cast(__half2, u));
}

// ---------------------------------------------------------------------------
// Kernel 1: blocks [0,2352): transpose x (B,C,H,W) -> split-bf16 xth/xtl (for
//           scores) + fp16 xh16 (for GEMM), all (B,HW,C).
//           blocks [2352,2640): W' = [C1;C2] -> fp16 wh16 (N=384, K=192)
// ---------------------------------------------------------------------------
__global__ __launch_bounds__(256) void k_pre(const float* __restrict__ x,
                                             const float* __restrict__ cw,
                                             unsigned short* __restrict__ xth,
                                             unsigned short* __restrict__ xtl,
                                             unsigned short* __restrict__ xh16,
                                             unsigned short* __restrict__ wh16) {
    int tid = threadIdx.x, bid = blockIdx.x;
    if (bid < 2352) {
        __shared__ float tile[32][33];
        int b = bid / 588, rem = bid % 588;
        int by = rem / 98, bx = rem % 98;
        int tx = tid & 31, ty = tid >> 5;
        int p0 = bx * 32, c0 = by * 32;
#pragma unroll
        for (int i = 0; i < 4; i++) {
            int c = c0 + ty + 8 * i;
            tile[ty + 8 * i][tx] = x[(b * CC + c) * HWW + p0 + tx];
        }
        __syncthreads();
#pragma unroll
        for (int i = 0; i < 4; i++) {
            int p = p0 + ty + 8 * i;
            float v = tile[tx][ty + 8 * i];
            unsigned short hi = f2b(v);
            size_t o = (size_t)(b * HWW + p) * CC + c0 + tx;
            xth[o] = hi;
            xtl[o] = f2b(v - b2f(hi));
            xh16[o] = f2h(v);
        }
    } else {
        int i = (bid - 2352) * 256 + tid;     // 288*256 = 73728 = 384*192 exact
        if (i < 384 * 192) {
            int n = i / 192, k = i % 192;
            float v = (n < 192) ? cw[n * 384 + k] : cw[(n - 192) * 384 + 192 + k];
            wh16[i] = f2h(v);
        }
    }
}

// ---------------------------------------------------------------------------
// Kernel 2 (fused independent work):
//   blocks [0,1792):    scores (pair symmetry, split-bf16 recon) -> sp
//   blocks [1792,2968): GEMM [u|z] = W'·x^T, M=12544, N=384, K=192, fp16
//                       single-MFMA (16x16x32_f16), LDS 18.4KB.
// ---------------------------------------------------------------------------
__global__ __launch_bounds__(256) void k_mid(const unsigned short* __restrict__ xth,
                                             const unsigned short* __restrict__ xtl,
                                             const unsigned short* __restrict__ xh16,
                                             const unsigned short* __restrict__ wh16,
                                             float* __restrict__ sp,
                                             float* __restrict__ u,
                                             float* __restrict__ z) {
    __shared__ __align__(16) char smem[18432];
    int tid = threadIdx.x, bid = blockIdx.x;

    if (bid < 1792) {                 // ---------------- scores ----------------
        float* Xs = (float*)smem;     // 28 rows x 96ch (+4 pad) -- 11.2KB
        const float K2 = 0.38490017945975050f;  // 2/sqrt(27)
        bool isH = bid < 896;
        int lid = isH ? bid : bid - 896;
        int half = lid & 1;
        int rp = (lid >> 1) & 1;
        int cb2 = lid >> 2;
        int b = cb2 / 56, l0 = cb2 % 56;
        int r0 = rp * 2;

        const unsigned short* srch = xth + (size_t)(b * HWW) * CC + half * 96;
        const unsigned short* srcl = xtl + (size_t)(b * HWW) * CC + half * 96;
        for (int idx = tid; idx < 28 * 12; idx += 256) {
            int t2 = idx / 12, cq = idx % 12;
            int pi = (r0 + t2 / 14) + 4 * (t2 % 14);
            int pix = isH ? (pi * WW + l0) : (l0 * WW + pi);
            short8 h8 = *(const short8*)(srch + (size_t)pix * CC + cq * 8);
            short8 l8 = *(const short8*)(srcl + (size_t)pix * CC + cq * 8);
            float o[8];
#pragma unroll
            for (int e = 0; e < 8; e++)
                o[e] = b2f((unsigned short)h8[e]) + b2f((unsigned short)l8[e]);
            *(float4*)&Xs[t2 * 100 + cq * 8] = *(float4*)&o[0];
            *(float4*)&Xs[t2 * 100 + cq * 8 + 4] = *(float4*)&o[4];
        }
        __syncthreads();

        int perCls = isH ? 105 : 91;
        if (tid < 2 * perCls) {
            int cls = tid / perCls, p = tid % perCls;
            int a, bb;
            if (isH) {
                a = (int)((sqrtf((float)(8 * p + 1)) - 1.0f) * 0.5f);
                bb = p - (a * (a + 1)) / 2;
            } else {
                int ap = (int)((sqrtf((float)(8 * p + 1)) - 1.0f) * 0.5f);
                bb = p - (ap * (ap + 1)) / 2;
                a = ap + 1;
            }
            const float* pA = &Xs[(cls * 14 + a) * 100];
            const float* pB = &Xs[(cls * 14 + bb) * 100];
            float s0 = 0.f, s1 = 0.f, s2 = 0.f, s3 = 0.f;
#pragma unroll
            for (int q = 0; q < 24; q++) {
                float4 av = *(const float4*)(pA + q * 4);
                float4 bv = *(const float4*)(pB + q * 4);
                s0 += __builtin_amdgcn_rcpf(__expf(av.x * bv.x * K2) + 1.0f);
                s1 += __builtin_amdgcn_rcpf(__expf(av.y * bv.y * K2) + 1.0f);
                s2 += __builtin_amdgcn_rcpf(__expf(av.z * bv.z * K2) + 1.0f);
                s3 += __builtin_amdgcn_rcpf(__expf(av.w * bv.w * K2) + 1.0f);
            }
            float s = 96.0f - 2.0f * (s0 + s1 + s2 + s3);   // sum_c tanh
            int r = r0 + cls;
            size_t base = (size_t)(half * BB + b) * HWW;
            if (isH) {
                int i1 = a - bb;
                int h1 = r + 4 * a, h2 = r + 4 * bb;
                sp[(base + h1 * WW + l0) * 32 + i1] = s;
                if (a != bb) sp[(base + h2 * WW + l0) * 32 + (14 - i1)] = s;
            } else {
                int d = a - bb;                        // 1..13
                int w1 = r + 4 * a, w2 = r + 4 * bb;
                sp[(base + l0 * WW + w1) * 32 + 14 + (d - 1)] = s;
                sp[(base + l0 * WW + w2) * 32 + 14 + (13 - d)] = s;
            }
        }
        return;
    }

    // ---------------- GEMM [u|z], fp16, tile 64x64, K=192 ----------------
    {
        unsigned short* Ah = (unsigned short*)smem;   // [64][72]
        unsigned short* Bh = Ah + 64 * 72;            // [64][72]
        float* Ds = (float*)smem;                     // reused for epilogue
        int vb = bid - 1792;                  // 0..1175
        int bm = (vb % 196) * 64, bn = (vb / 196) * 64;
        int lane = tid & 63, wv = tid >> 6;

        f32x4 acc[4] = {{0,0,0,0},{0,0,0,0},{0,0,0,0},{0,0,0,0}};

        for (int kc = 0; kc < 3; kc++) {
#pragma unroll
            for (int r2 = 0; r2 < 2; r2++) {
                int idx = tid + r2 * 256;
                int m = idx >> 3, kq = idx & 7;
                size_t ao = (size_t)(bm + m) * CC + kc * 64 + kq * 8;
                *(short8*)&Ah[m * 72 + kq * 8] = *(const short8*)(xh16 + ao);
                size_t bo = (size_t)(bn + m) * 192 + kc * 64 + kq * 8;
                *(short8*)&Bh[m * 72 + kq * 8] = *(const short8*)(wh16 + bo);
            }
            __syncthreads();
            int n0 = wv * 16;
            int k8 = lane >> 4;
            int col = lane & 15;
#pragma unroll
            for (int ks = 0; ks < 64; ks += 32) {
                int koff = ks + k8 * 8;
                half8 bf = *(const half8*)&Bh[(n0 + col) * 72 + koff];
#pragma unroll
                for (int fm = 0; fm < 4; fm++) {
                    half8 af = *(const half8*)&Ah[(fm * 16 + col) * 72 + koff];
                    acc[fm] = __builtin_amdgcn_mfma_f32_16x16x32_f16(af, bf, acc[fm], 0, 0, 0);
                }
            }
            __syncthreads();
        }
        // LDS transpose: Ds[m][n], stride 68
        {
            int col = lane & 15, rowq = lane >> 4;
#pragma unroll
            for (int fm = 0; fm < 4; fm++)
#pragma unroll
                for (int rg = 0; rg < 4; rg++)
                    Ds[(fm * 16 + rowq * 4 + rg) * 68 + wv * 16 + col] = acc[fm][rg];
        }
        __syncthreads();
        // Store pixel-major: u (n<192) or z (n>=192)
        {
            int c4 = tid & 15, m0 = tid >> 4;
            int cg = bn + c4 * 4;
            float* dst = (cg < 192) ? u : z;
            int cc = (cg < 192) ? cg : cg - 192;
#pragma unroll
            for (int p = 0; p < 4; p++) {
                int m = m0 + p * 16;
                float4 v = *(float4*)&Ds[m * 68 + c4 * 4];
                *(float4*)&dst[(size_t)(bm + m) * CC + cc] = v;
            }
        }
    }
}

// ---------------------------------------------------------------------------
// Kernel 3: fused softmax + H+W accumulation + bias + BN + GELU.
// Block = (b, r-phase, 8-ch chunk, t-half). LDS: z slab (25KB) + per-block
// f16 weight slab W16 (28KB) computed IN-BLOCK: one softmax per pixel per
// block (392 softmaxes, 1 per thread), replacing the separate k_soft kernel
// and the wn16 global round-trip. z staging is issue-early/write-late so the
// global loads' latency hides under the softmax exp work.
// Grid 768 = 4b x 4r x 24cc x 2th, 448 threads (tid = w*8+c).
// ---------------------------------------------------------------------------
__global__ __launch_bounds__(448, 1) void k_tail(const float* __restrict__ u,
                                                 const float* __restrict__ z,
                                                 const float* __restrict__ sp,
                                                 const float* __restrict__ cb,
                                                 const float* __restrict__ gma,
                                                 const float* __restrict__ bta,
                                                 const float* __restrict__ mea,
                                                 const float* __restrict__ var,
                                                 float* __restrict__ y) {
    __shared__ float Zs[14 * 56 * 8];                         // 25088 B, [t][w][c]
    __shared__ __align__(16) unsigned short W16[392 * 36];    // 28224 B, [pixlocal][36]
    int tid = threadIdx.x, bid = blockIdx.x;
    int th = bid & 1;
    int t1 = bid >> 1;                    // 0..383
    int cc = t1 % 24;
    int t2 = t1 / 24;                     // 0..15
    int r = t2 & 3;
    int b = t2 >> 2;
    int w = tid >> 3, c = tid & 7;
    int cg = cc * 8 + c;
    int hbase = r + 4 * (th * 7);

    // (1) issue z-slab loads into registers (write to LDS deferred: T14 split)
    float4 zva0, zva1, zvb0, zvb1;
    {
        int idx = tid;                    // < 784 always (448)
        int t = idx / 56, ww = idx - t * 56;
        const float* s = z + ((size_t)(b * HWW + (r + 4 * t) * WW + ww)) * CC + cc * 8;
        zva0 = *(const float4*)s;
        zva1 = *(const float4*)(s + 4);
    }
    if (tid < 336) {
        int idx = tid + 448;
        int t = idx / 56, ww = idx - t * 56;
        const float* s = z + ((size_t)(b * HWW + (r + 4 * t) * WW + ww)) * CC + cc * 8;
        zvb0 = *(const float4*)s;
        zvb1 = *(const float4*)(s + 4);
    }

    // (2) softmax: one pixel per thread (392 pixels), weights -> W16 LDS
    if (tid < 392) {
        int tq = tid / 56, ww = tid - tq * 56;
        int row = hbase + 4 * tq;
        size_t gp = (size_t)b * HWW + row * WW + ww;
        const float4* p0 = (const float4*)&sp[gp * 32];
        const float4* p1 = (const float4*)&sp[((size_t)(4 * HWW) + gp) * 32];
        float sc[28];
#pragma unroll
        for (int j = 0; j < 7; j++) {
            float4 a4 = p0[j], v4 = p1[j];
            sc[4 * j + 0] = a4.x + v4.x; sc[4 * j + 1] = a4.y + v4.y;
            sc[4 * j + 2] = a4.z + v4.z; sc[4 * j + 3] = a4.w + v4.w;
        }
        float mx = -1e30f;
#pragma unroll
        for (int s = 0; s < 27; s++) mx = fmaxf(mx, sc[s]);
        float sum = 0.f;
#pragma unroll
        for (int s = 0; s < 27; s++) { sc[s] = __expf(sc[s] - mx); sum += sc[s]; }
        float inv = __builtin_amdgcn_rcpf(sum);
        unsigned short hw[28];
#pragma unroll
        for (int s = 0; s < 27; s++) hw[s] = f2h(sc[s] * inv);
        hw[27] = 0;
        unsigned short* d = &W16[tid * 36];
        *(short8*)(d)      = *(short8*)&hw[0];
        *(short8*)(d + 8)  = *(short8*)&hw[8];
        *(short8*)(d + 16) = *(short8*)&hw[16];
        *(short4v*)(d + 24) = *(short4v*)&hw[24];
    }

    // (3) write z registers to LDS, then one barrier
    {
        float* dst = &Zs[tid * 8];
        *(float4*)dst = zva0;
        *(float4*)(dst + 4) = zva1;
    }
    if (tid < 336) {
        float* dst = &Zs[(tid + 448) * 8];
        *(float4*)dst = zvb0;
        *(float4*)(dst + 4) = zvb1;
    }
    __syncthreads();

    // this thread's z column, pre-rotated by th*7 so all reg indices are static
    float zc[14];
#pragma unroll
    for (int m = 0; m < 14; m++) {
        int t0 = m + th * 7;
        if (t0 >= 14) t0 -= 14;
        zc[m] = Zs[(t0 * 56 + w) * 8 + c];
    }

    float bias = cb[cg];
    float ginv = gma[cg] * rsqrtf(var[cg] + 1e-5f);
    float bt = bta[cg];
    float me = mea[cg];

    float acc0[7];
#pragma unroll
    for (int tt = 0; tt < 7; tt++) {
        int pix = (hbase + 4 * tt) * WW + w;
        acc0[tt] = u[((size_t)(b * HWW + pix)) * CC + cg];
    }

#pragma unroll
    for (int tt = 0; tt < 7; tt++) {
        int t = th * 7 + tt;
        int pix = (hbase + 4 * tt) * WW + w;
        int pb = (tt * 56 + w) * 36;
        float a = acc0[tt];

        // H-part: halves 0..13 = wt[i], zc rotated so indices are static
#pragma unroll
        for (int p = 0; p < 7; p++) {
            float2 f2 = h2f2(*(const unsigned int*)&W16[pb + 2 * p]);
            a += f2.x * zc[(tt - 2 * p + 28) % 14];
            a += f2.y * zc[(tt - 2 * p - 1 + 28) % 14];
        }
        // W-part: halves 14..26 = wt[13+j] (j=1..13); half 27 = 0 pad
#pragma unroll
        for (int p = 7; p < 14; p++) {
            float2 f2 = h2f2(*(const unsigned int*)&W16[pb + 2 * p]);
            int j0 = 2 * p - 13, j1 = 2 * p - 12;
            int wj0 = w - 4 * j0; if (wj0 < 0) wj0 += 56;
            int wj1 = w - 4 * j1; if (wj1 < 0) wj1 += 56;
            a += f2.x * Zs[(t * 56 + wj0) * 8 + c];
            a += f2.y * Zs[(t * 56 + wj1) * 8 + c];
        }

        float v = (a + bias - me) * ginv + bt;
        v = 0.5f * v * (1.0f + erff(v * 0.70710678118654752f));
        y[((size_t)(b * CC + cg)) * HWW + pix] = v;
    }
}

// ---------------------------------------------------------------------------
extern "C" void kernel_launch(void* const* d_in, const int* in_sizes, int n_in,
                              void* d_out, int out_size, void* d_ws, size_t ws_size,
                              hipStream_t stream) {
    const float* x   = (const float*)d_in[0];
    const float* cw  = (const float*)d_in[1];
    const float* cb  = (const float*)d_in[2];
    const float* gma = (const float*)d_in[3];
    const float* bta = (const float*)d_in[4];
    const float* mea = (const float*)d_in[5];
    const float* var = (const float*)d_in[6];
    float* out = (float*)d_out;

    float* ws = (float*)d_ws;
    float*          sp   = ws;                                  //   802,816 f
    float*          u    = ws + 802816;                         // 2,408,448 f
    float*          z    = ws + 3211264;                        // 2,408,448 f
    unsigned short* xth  = (unsigned short*)(ws + 5619712);     // 2,408,448 us
    unsigned short* xtl  = (unsigned short*)(ws + 6823936);     // 2,408,448 us
    unsigned short* xh16 = (unsigned short*)(ws + 8028160);     // 2,408,448 us -> ends 9,232,384
    unsigned short* wh16 = (unsigned short*)(ws + 9232384);     //    73,728 us

    k_pre<<<2640, 256, 0, stream>>>(x, cw, xth, xtl, xh16, wh16);
    k_mid<<<2968, 256, 0, stream>>>(xth, xtl, xh16, wh16, sp, u, z);
    k_tail<<<768, 448, 0, stream>>>(u, z, sp, cb, gma, bta, mea, var, out);
}

// Round 9
// 121.571 us; speedup vs baseline: 1.0420x; 1.0350x over previous
//
#include <hip/hip_runtime.h>
#include <hip/hip_bf16.h>
#include <hip/hip_fp16.h>
#include <math.h>

#define BB 4
#define CC 192
#define HH 56
#define WW 56
#define HWW 3136

typedef __attribute__((ext_vector_type(8))) short short8;
typedef __attribute__((ext_vector_type(4))) short short4v;
typedef __attribute__((ext_vector_type(8))) _Float16 half8;
typedef __attribute__((ext_vector_type(4))) float f32x4;

__device__ __forceinline__ unsigned short f2b(float f) {
    __hip_bfloat16 h = __float2bfloat16(f);
    return __builtin_bit_cast(unsigned short, h);
}
__device__ __forceinline__ float b2f(unsigned short u) {
    unsigned int x = ((unsigned int)u) << 16;
    return __builtin_bit_cast(float, x);
}
__device__ __forceinline__ unsigned short f2h(float f) {
    __half h = __float2half_rn(f);
    return __builtin_bit_cast(unsigned short, h);
}
__device__ __forceinline__ float2 h2f2(unsigned int u) {
    return __half22float2(__builtin_bit_cast(__half2, u));
}

// ---------------------------------------------------------------------------
// Kernel 1: blocks [0,2352): transpose x (B,C,H,W) -> split-bf16 xth/xtl (for
//           scores) + fp16 xh16 (for GEMM), all (B,HW,C).
//           blocks [2352,2640): W' = [C1;C2] -> fp16 wh16 (N=384, K=192)
// ---------------------------------------------------------------------------
__global__ __launch_bounds__(256) void k_pre(const float* __restrict__ x,
                                             const float* __restrict__ cw,
                                             unsigned short* __restrict__ xth,
                                             unsigned short* __restrict__ xtl,
                                             unsigned short* __restrict__ xh16,
                                             unsigned short* __restrict__ wh16) {
    int tid = threadIdx.x, bid = blockIdx.x;
    if (bid < 2352) {
        __shared__ float tile[32][33];
        int b = bid / 588, rem = bid % 588;
        int by = rem / 98, bx = rem % 98;
        int tx = tid & 31, ty = tid >> 5;
        int p0 = bx * 32, c0 = by * 32;
#pragma unroll
        for (int i = 0; i < 4; i++) {
            int c = c0 + ty + 8 * i;
            tile[ty + 8 * i][tx] = x[(b * CC + c) * HWW + p0 + tx];
        }
        __syncthreads();
#pragma unroll
        for (int i = 0; i < 4; i++) {
            int p = p0 + ty + 8 * i;
            float v = tile[tx][ty + 8 * i];
            unsigned short hi = f2b(v);
            size_t o = (size_t)(b * HWW + p) * CC + c0 + tx;
            xth[o] = hi;
            xtl[o] = f2b(v - b2f(hi));
            xh16[o] = f2h(v);
        }
    } else {
        int i = (bid - 2352) * 256 + tid;     // 288*256 = 73728 = 384*192 exact
        if (i < 384 * 192) {
            int n = i / 192, k = i % 192;
            float v = (n < 192) ? cw[n * 384 + k] : cw[(n - 192) * 384 + 192 + k];
            wh16[i] = f2h(v);
        }
    }
}

// ---------------------------------------------------------------------------
// Kernel 2 (fused independent work):
//   blocks [0,1792):    scores (pair symmetry, split-bf16 recon) -> sp
//   blocks [1792,2968): GEMM [u|z] = W'·x^T, fp16 MFMA.
//   u/z are stored SLAB-NATIVE for k_tail: [cc8][b][r][t][w][8c]
//   (slab stride 6272 floats = 14t*56w*8c; 384 slabs = 24cc8*4b*4r).
// ---------------------------------------------------------------------------
__global__ __launch_bounds__(256) void k_mid(const unsigned short* __restrict__ xth,
                                             const unsigned short* __restrict__ xtl,
                                             const unsigned short* __restrict__ xh16,
                                             const unsigned short* __restrict__ wh16,
                                             float* __restrict__ sp,
                                             float* __restrict__ u,
                                             float* __restrict__ z) {
    __shared__ __align__(16) char smem[18432];
    int tid = threadIdx.x, bid = blockIdx.x;

    if (bid < 1792) {                 // ---------------- scores ----------------
        float* Xs = (float*)smem;     // 28 rows x 96ch (+4 pad) -- 11.2KB
        const float K2 = 0.38490017945975050f;  // 2/sqrt(27)
        bool isH = bid < 896;
        int lid = isH ? bid : bid - 896;
        int half = lid & 1;
        int rp = (lid >> 1) & 1;
        int cb2 = lid >> 2;
        int b = cb2 / 56, l0 = cb2 % 56;
        int r0 = rp * 2;

        const unsigned short* srch = xth + (size_t)(b * HWW) * CC + half * 96;
        const unsigned short* srcl = xtl + (size_t)(b * HWW) * CC + half * 96;
        for (int idx = tid; idx < 28 * 12; idx += 256) {
            int t2 = idx / 12, cq = idx % 12;
            int pi = (r0 + t2 / 14) + 4 * (t2 % 14);
            int pix = isH ? (pi * WW + l0) : (l0 * WW + pi);
            short8 h8 = *(const short8*)(srch + (size_t)pix * CC + cq * 8);
            short8 l8 = *(const short8*)(srcl + (size_t)pix * CC + cq * 8);
            float o[8];
#pragma unroll
            for (int e = 0; e < 8; e++)
                o[e] = b2f((unsigned short)h8[e]) + b2f((unsigned short)l8[e]);
            *(float4*)&Xs[t2 * 100 + cq * 8] = *(float4*)&o[0];
            *(float4*)&Xs[t2 * 100 + cq * 8 + 4] = *(float4*)&o[4];
        }
        __syncthreads();

        int perCls = isH ? 105 : 91;
        if (tid < 2 * perCls) {
            int cls = tid / perCls, p = tid % perCls;
            int a, bb;
            if (isH) {
                a = (int)((sqrtf((float)(8 * p + 1)) - 1.0f) * 0.5f);
                bb = p - (a * (a + 1)) / 2;
            } else {
                int ap = (int)((sqrtf((float)(8 * p + 1)) - 1.0f) * 0.5f);
                bb = p - (ap * (ap + 1)) / 2;
                a = ap + 1;
            }
            const float* pA = &Xs[(cls * 14 + a) * 100];
            const float* pB = &Xs[(cls * 14 + bb) * 100];
            float s0 = 0.f, s1 = 0.f, s2 = 0.f, s3 = 0.f;
#pragma unroll
            for (int q = 0; q < 24; q++) {
                float4 av = *(const float4*)(pA + q * 4);
                float4 bv = *(const float4*)(pB + q * 4);
                s0 += __builtin_amdgcn_rcpf(__expf(av.x * bv.x * K2) + 1.0f);
                s1 += __builtin_amdgcn_rcpf(__expf(av.y * bv.y * K2) + 1.0f);
                s2 += __builtin_amdgcn_rcpf(__expf(av.z * bv.z * K2) + 1.0f);
                s3 += __builtin_amdgcn_rcpf(__expf(av.w * bv.w * K2) + 1.0f);
            }
            float s = 96.0f - 2.0f * (s0 + s1 + s2 + s3);   // sum_c tanh
            int r = r0 + cls;
            size_t base = (size_t)(half * BB + b) * HWW;
            if (isH) {
                int i1 = a - bb;
                int h1 = r + 4 * a, h2 = r + 4 * bb;
                sp[(base + h1 * WW + l0) * 32 + i1] = s;
                if (a != bb) sp[(base + h2 * WW + l0) * 32 + (14 - i1)] = s;
            } else {
                int d = a - bb;                        // 1..13
                int w1 = r + 4 * a, w2 = r + 4 * bb;
                sp[(base + l0 * WW + w1) * 32 + 14 + (d - 1)] = s;
                sp[(base + l0 * WW + w2) * 32 + 14 + (13 - d)] = s;
            }
        }
        return;
    }

    // ---------------- GEMM [u|z], fp16, tile 64x64, K=192 ----------------
    {
        unsigned short* Ah = (unsigned short*)smem;   // [64][72]
        unsigned short* Bh = Ah + 64 * 72;            // [64][72]
        float* Ds = (float*)smem;                     // reused for epilogue
        int vb = bid - 1792;                  // 0..1175
        int bm = (vb % 196) * 64, bn = (vb / 196) * 64;
        int lane = tid & 63, wv = tid >> 6;

        f32x4 acc[4] = {{0,0,0,0},{0,0,0,0},{0,0,0,0},{0,0,0,0}};

        for (int kc = 0; kc < 3; kc++) {
#pragma unroll
            for (int r2 = 0; r2 < 2; r2++) {
                int idx = tid + r2 * 256;
                int m = idx >> 3, kq = idx & 7;
                size_t ao = (size_t)(bm + m) * CC + kc * 64 + kq * 8;
                *(short8*)&Ah[m * 72 + kq * 8] = *(const short8*)(xh16 + ao);
                size_t bo = (size_t)(bn + m) * 192 + kc * 64 + kq * 8;
                *(short8*)&Bh[m * 72 + kq * 8] = *(const short8*)(wh16 + bo);
            }
            __syncthreads();
            int n0 = wv * 16;
            int k8 = lane >> 4;
            int col = lane & 15;
#pragma unroll
            for (int ks = 0; ks < 64; ks += 32) {
                int koff = ks + k8 * 8;
                half8 bf = *(const half8*)&Bh[(n0 + col) * 72 + koff];
#pragma unroll
                for (int fm = 0; fm < 4; fm++) {
                    half8 af = *(const half8*)&Ah[(fm * 16 + col) * 72 + koff];
                    acc[fm] = __builtin_amdgcn_mfma_f32_16x16x32_f16(af, bf, acc[fm], 0, 0, 0);
                }
            }
            __syncthreads();
        }
        // LDS transpose: Ds[m][n], stride 68
        {
            int col = lane & 15, rowq = lane >> 4;
#pragma unroll
            for (int fm = 0; fm < 4; fm++)
#pragma unroll
                for (int rg = 0; rg < 4; rg++)
                    Ds[(fm * 16 + rowq * 4 + rg) * 68 + wv * 16 + col] = acc[fm][rg];
        }
        __syncthreads();
        // Store slab-native: dst[((cc8*4+b)*4+r)*6272 + t*448 + w*8 + ci]
        {
            int c4 = tid & 15, m0 = tid >> 4;
            int cg = bn + c4 * 4;
            float* dst = (cg < 192) ? u : z;
            int cc = (cg < 192) ? cg : cg - 192;
            int cc8 = cc >> 3, ci = cc & 7;           // ci in {0,4}
            size_t cbase = (size_t)cc8 * 100352;      // 4b*4r*14t*448
#pragma unroll
            for (int p = 0; p < 4; p++) {
                int m = m0 + p * 16;
                int gp = bm + m;
                int b = gp / HWW, pp = gp - b * HWW;
                int hh = pp / 56, ww2 = pp - hh * 56;
                int rr = hh & 3, tt2 = hh >> 2;
                size_t off = cbase + ((size_t)((b * 4 + rr) * 14 + tt2)) * 448 + ww2 * 8 + ci;
                float4 v = *(float4*)&Ds[m * 68 + c4 * 4];
                *(float4*)&dst[off] = v;
            }
        }
    }
}

// ---------------------------------------------------------------------------
// Kernel 3: fused softmax + H+W accumulation + bias + BN + GELU.
// Block = (b, r, cc8, th). u/z are slab-native: block's z slab is one
// CONTIGUOUS 25KB stream; u reads are dense 448-float rows; y written via
// 12.5KB LDS restage (aliased over W16) as contiguous 224B channel-rows.
// Grid 768 = 4b x 4r x 24cc x 2th, 448 threads (tid = w*8+c).
// ---------------------------------------------------------------------------
__global__ __launch_bounds__(448, 1) void k_tail(const float* __restrict__ u,
                                                 const float* __restrict__ z,
                                                 const float* __restrict__ sp,
                                                 const float* __restrict__ cb,
                                                 const float* __restrict__ gma,
                                                 const float* __restrict__ bta,
                                                 const float* __restrict__ mea,
                                                 const float* __restrict__ var,
                                                 float* __restrict__ y) {
    __shared__ __align__(16) char arena[25088 + 28224];       // 53312 B
    float* Zs = (float*)arena;                                // [t][w][c] 25088B
    unsigned short* W16 = (unsigned short*)(arena + 25088);   // [pixl][36] 28224B
    float* Ys = (float*)(arena + 25088);                      // 7*448 f, aliased

    int tid = threadIdx.x, bid = blockIdx.x;
    int th = bid & 1;
    int t1 = bid >> 1;                    // 0..383
    int cc = t1 % 24;
    int t2 = t1 / 24;                     // 0..15
    int r = t2 & 3;
    int b = t2 >> 2;
    int w = tid >> 3, c = tid & 7;
    int cg = cc * 8 + c;
    int hbase = r + 4 * (th * 7);

    size_t slab = ((size_t)cc * BB + b) * 4 + r;
    const float* zg = z + slab * 6272;
    const float* ug = u + slab * 6272;

    // (1) issue slab loads early (contiguous, fully coalesced); write LDS late
    float4 zva0 = *(const float4*)(zg + tid * 8);
    float4 zva1 = *(const float4*)(zg + tid * 8 + 4);
    float4 zvb0, zvb1;
    if (tid < 336) {
        zvb0 = *(const float4*)(zg + (tid + 448) * 8);
        zvb1 = *(const float4*)(zg + (tid + 448) * 8 + 4);
    }
    float acc0[7];
#pragma unroll
    for (int tt = 0; tt < 7; tt++)
        acc0[tt] = ug[(th * 7 + tt) * 448 + tid];

    // (2) softmax: one pixel per thread (392 pixels), weights -> W16 LDS
    if (tid < 392) {
        int tq = tid / 56, ww = tid - tq * 56;
        int row = hbase + 4 * tq;
        size_t gp = (size_t)b * HWW + row * WW + ww;
        const float4* p0 = (const float4*)&sp[gp * 32];
        const float4* p1 = (const float4*)&sp[((size_t)(4 * HWW) + gp) * 32];
        float sc[28];
#pragma unroll
        for (int j = 0; j < 7; j++) {
            float4 a4 = p0[j], v4 = p1[j];
            sc[4 * j + 0] = a4.x + v4.x; sc[4 * j + 1] = a4.y + v4.y;
            sc[4 * j + 2] = a4.z + v4.z; sc[4 * j + 3] = a4.w + v4.w;
        }
        float mx = -1e30f;
#pragma unroll
        for (int s = 0; s < 27; s++) mx = fmaxf(mx, sc[s]);
        float sum = 0.f;
#pragma unroll
        for (int s = 0; s < 27; s++) { sc[s] = __expf(sc[s] - mx); sum += sc[s]; }
        float inv = __builtin_amdgcn_rcpf(sum);
        unsigned short hw[28];
#pragma unroll
        for (int s = 0; s < 27; s++) hw[s] = f2h(sc[s] * inv);
        hw[27] = 0;
        unsigned short* d = &W16[tid * 36];
        *(short8*)(d)      = *(short8*)&hw[0];
        *(short8*)(d + 8)  = *(short8*)&hw[8];
        *(short8*)(d + 16) = *(short8*)&hw[16];
        *(short4v*)(d + 24) = *(short4v*)&hw[24];
    }

    // (3) write z registers to LDS (layout identical to global slab), barrier
    {
        float* dst = &Zs[tid * 8];
        *(float4*)dst = zva0;
        *(float4*)(dst + 4) = zva1;
    }
    if (tid < 336) {
        float* dst = &Zs[(tid + 448) * 8];
        *(float4*)dst = zvb0;
        *(float4*)(dst + 4) = zvb1;
    }
    __syncthreads();

    // (4) compute
    float zc[14];
#pragma unroll
    for (int m = 0; m < 14; m++) {
        int t0 = m + th * 7;
        if (t0 >= 14) t0 -= 14;
        zc[m] = Zs[(t0 * 56 + w) * 8 + c];
    }

    float bias = cb[cg];
    float ginv = gma[cg] * rsqrtf(var[cg] + 1e-5f);
    float bt = bta[cg];
    float me = mea[cg];

    float vout[7];
#pragma unroll
    for (int tt = 0; tt < 7; tt++) {
        int t = th * 7 + tt;
        int pb = (tt * 56 + w) * 36;
        float a = acc0[tt];

        // H-part: halves 0..13 = wt[i], zc rotated so indices are static
#pragma unroll
        for (int p = 0; p < 7; p++) {
            float2 f2 = h2f2(*(const unsigned int*)&W16[pb + 2 * p]);
            a += f2.x * zc[(tt - 2 * p + 28) % 14];
            a += f2.y * zc[(tt - 2 * p - 1 + 28) % 14];
        }
        // W-part: halves 14..26 = wt[13+j] (j=1..13); half 27 = 0 pad
#pragma unroll
        for (int p = 7; p < 14; p++) {
            float2 f2 = h2f2(*(const unsigned int*)&W16[pb + 2 * p]);
            int j0 = 2 * p - 13, j1 = 2 * p - 12;
            int wj0 = w - 4 * j0; if (wj0 < 0) wj0 += 56;
            int wj1 = w - 4 * j1; if (wj1 < 0) wj1 += 56;
            a += f2.x * Zs[(t * 56 + wj0) * 8 + c];
            a += f2.y * Zs[(t * 56 + wj1) * 8 + c];
        }

        float v = (a + bias - me) * ginv + bt;
        vout[tt] = 0.5f * v * (1.0f + erff(v * 0.70710678118654752f));
    }

    // (5) output restage: Ys aliases W16 (compute done), coalesced y stores
    __syncthreads();
#pragma unroll
    for (int tt = 0; tt < 7; tt++)
        Ys[tt * 448 + c * 56 + w] = vout[tt];
    __syncthreads();
    {
        int c_out = tid / 56, w_out = tid - c_out * 56;
        size_t ybase = ((size_t)(b * CC + cc * 8 + c_out)) * HWW + w_out;
#pragma unroll
        for (int tt = 0; tt < 7; tt++)
            y[ybase + (size_t)(hbase + 4 * tt) * 56] = Ys[tt * 448 + c_out * 56 + w_out];
    }
}

// ---------------------------------------------------------------------------
extern "C" void kernel_launch(void* const* d_in, const int* in_sizes, int n_in,
                              void* d_out, int out_size, void* d_ws, size_t ws_size,
                              hipStream_t stream) {
    const float* x   = (const float*)d_in[0];
    const float* cw  = (const float*)d_in[1];
    const float* cb  = (const float*)d_in[2];
    const float* gma = (const float*)d_in[3];
    const float* bta = (const float*)d_in[4];
    const float* mea = (const float*)d_in[5];
    const float* var = (const float*)d_in[6];
    float* out = (float*)d_out;

    float* ws = (float*)d_ws;
    float*          sp   = ws;                                  //   802,816 f
    float*          u    = ws + 802816;                         // 2,408,448 f (slab-native)
    float*          z    = ws + 3211264;                        // 2,408,448 f (slab-native)
    unsigned short* xth  = (unsigned short*)(ws + 5619712);     // 2,408,448 us
    unsigned short* xtl  = (unsigned short*)(ws + 6823936);     // 2,408,448 us
    unsigned short* xh16 = (unsigned short*)(ws + 8028160);     // 2,408,448 us -> ends 9,232,384
    unsigned short* wh16 = (unsigned short*)(ws + 9232384);     //    73,728 us

    k_pre<<<2640, 256, 0, stream>>>(x, cw, xth, xtl, xh16, wh16);
    k_mid<<<2968, 256, 0, stream>>>(xth, xtl, xh16, wh16, sp, u, z);
    k_tail<<<768, 448, 0, stream>>>(u, z, sp, cb, gma, bta, mea, var, out);
}

// Round 10
// 117.726 us; speedup vs baseline: 1.0760x; 1.0327x over previous
//
#include <hip/hip_runtime.h>
#include <hip/hip_bf16.h>
#include <hip/hip_fp16.h>
#include <math.h>

#define BB 4
#define CC 192
#define HH 56
#define WW 56
#define HWW 3136

typedef __attribute__((ext_vector_type(8))) short short8;
typedef __attribute__((ext_vector_type(4))) short short4v;
typedef __attribute__((ext_vector_type(8))) _Float16 half8;
typedef __attribute__((ext_vector_type(4))) float f32x4;

__device__ __forceinline__ unsigned short f2h(float f) {
    __half h = __float2half_rn(f);
    return __builtin_bit_cast(unsigned short, h);
}
__device__ __forceinline__ float2 h2f2(unsigned int u) {
    return __half22float2(__builtin_bit_cast(__half2, u));
}

// ---------------------------------------------------------------------------
// Kernel 1: blocks [0,2352): transpose x (B,C,H,W) -> fp16 xh16 (B,HW,C)
//           blocks [2352,2640): W' = [C1;C2] -> fp16 wh16 (N=384, K=192)
// fp16 x serves BOTH the scores (rel err 5e-4, see error analysis) and GEMM.
// ---------------------------------------------------------------------------
__global__ __launch_bounds__(256) void k_pre(const float* __restrict__ x,
                                             const float* __restrict__ cw,
                                             unsigned short* __restrict__ xh16,
                                             unsigned short* __restrict__ wh16) {
    int tid = threadIdx.x, bid = blockIdx.x;
    if (bid < 2352) {
        __shared__ float tile[32][33];
        int b = bid / 588, rem = bid % 588;
        int by = rem / 98, bx = rem % 98;
        int tx = tid & 31, ty = tid >> 5;
        int p0 = bx * 32, c0 = by * 32;
#pragma unroll
        for (int i = 0; i < 4; i++) {
            int c = c0 + ty + 8 * i;
            tile[ty + 8 * i][tx] = x[(b * CC + c) * HWW + p0 + tx];
        }
        __syncthreads();
#pragma unroll
        for (int i = 0; i < 4; i++) {
            int p = p0 + ty + 8 * i;
            float v = tile[tx][ty + 8 * i];
            size_t o = (size_t)(b * HWW + p) * CC + c0 + tx;
            xh16[o] = f2h(v);
        }
    } else {
        int i = (bid - 2352) * 256 + tid;     // 288*256 = 73728 = 384*192 exact
        if (i < 384 * 192) {
            int n = i / 192, k = i % 192;
            float v = (n < 192) ? cw[n * 384 + k] : cw[(n - 192) * 384 + 192 + k];
            wh16[i] = f2h(v);
        }
    }
}

// ---------------------------------------------------------------------------
// Kernel 2 (fused independent work):
//   blocks [0,1792):    scores (pair symmetry, fp16 x) -> sp
//   blocks [1792,2968): GEMM [u|z] = W'·x^T, fp16 MFMA, slab-native output.
// ---------------------------------------------------------------------------
__global__ __launch_bounds__(256) void k_mid(const unsigned short* __restrict__ xh16,
                                             const unsigned short* __restrict__ wh16,
                                             float* __restrict__ sp,
                                             float* __restrict__ u,
                                             float* __restrict__ z) {
    __shared__ __align__(16) char smem[18432];
    int tid = threadIdx.x, bid = blockIdx.x;

    if (bid < 1792) {                 // ---------------- scores ----------------
        float* Xs = (float*)smem;     // 28 rows x 96ch (+4 pad) -- 11.2KB
        const float K2 = 0.38490017945975050f;  // 2/sqrt(27)
        bool isH = bid < 896;
        int lid = isH ? bid : bid - 896;
        int half = lid & 1;
        int rp = (lid >> 1) & 1;
        int cb2 = lid >> 2;
        int b = cb2 / 56, l0 = cb2 % 56;
        int r0 = rp * 2;

        const unsigned short* srcq = xh16 + (size_t)(b * HWW) * CC + half * 96;
        for (int idx = tid; idx < 28 * 12; idx += 256) {
            int t2 = idx / 12, cq = idx % 12;
            int pi = (r0 + t2 / 14) + 4 * (t2 % 14);
            int pix = isH ? (pi * WW + l0) : (l0 * WW + pi);
            uint4 hv = *(const uint4*)(srcq + (size_t)pix * CC + cq * 8);
            float2 f0 = h2f2(hv.x), f1 = h2f2(hv.y);
            float2 f2v = h2f2(hv.z), f3 = h2f2(hv.w);
            *(float4*)&Xs[t2 * 100 + cq * 8]     = make_float4(f0.x, f0.y, f1.x, f1.y);
            *(float4*)&Xs[t2 * 100 + cq * 8 + 4] = make_float4(f2v.x, f2v.y, f3.x, f3.y);
        }
        __syncthreads();

        int perCls = isH ? 105 : 91;
        if (tid < 2 * perCls) {
            int cls = tid / perCls, p = tid % perCls;
            int a, bb;
            if (isH) {
                a = (int)((sqrtf((float)(8 * p + 1)) - 1.0f) * 0.5f);
                bb = p - (a * (a + 1)) / 2;
            } else {
                int ap = (int)((sqrtf((float)(8 * p + 1)) - 1.0f) * 0.5f);
                bb = p - (ap * (ap + 1)) / 2;
                a = ap + 1;
            }
            const float* pA = &Xs[(cls * 14 + a) * 100];
            const float* pB = &Xs[(cls * 14 + bb) * 100];
            float s0 = 0.f, s1 = 0.f, s2 = 0.f, s3 = 0.f;
#pragma unroll
            for (int q = 0; q < 24; q++) {
                float4 av = *(const float4*)(pA + q * 4);
                float4 bv = *(const float4*)(pB + q * 4);
                s0 += __builtin_amdgcn_rcpf(__expf(av.x * bv.x * K2) + 1.0f);
                s1 += __builtin_amdgcn_rcpf(__expf(av.y * bv.y * K2) + 1.0f);
                s2 += __builtin_amdgcn_rcpf(__expf(av.z * bv.z * K2) + 1.0f);
                s3 += __builtin_amdgcn_rcpf(__expf(av.w * bv.w * K2) + 1.0f);
            }
            float s = 96.0f - 2.0f * (s0 + s1 + s2 + s3);   // sum_c tanh
            int r = r0 + cls;
            size_t base = (size_t)(half * BB + b) * HWW;
            if (isH) {
                int i1 = a - bb;
                int h1 = r + 4 * a, h2 = r + 4 * bb;
                sp[(base + h1 * WW + l0) * 32 + i1] = s;
                if (a != bb) sp[(base + h2 * WW + l0) * 32 + (14 - i1)] = s;
            } else {
                int d = a - bb;                        // 1..13
                int w1 = r + 4 * a, w2 = r + 4 * bb;
                sp[(base + l0 * WW + w1) * 32 + 14 + (d - 1)] = s;
                sp[(base + l0 * WW + w2) * 32 + 14 + (13 - d)] = s;
            }
        }
        return;
    }

    // ---------------- GEMM [u|z], fp16, tile 64x64, K=192 ----------------
    {
        unsigned short* Ah = (unsigned short*)smem;   // [64][72]
        unsigned short* Bh = Ah + 64 * 72;            // [64][72]
        float* Ds = (float*)smem;                     // reused for epilogue
        int vb = bid - 1792;                  // 0..1175
        int bm = (vb % 196) * 64, bn = (vb / 196) * 64;
        int lane = tid & 63, wv = tid >> 6;

        f32x4 acc[4] = {{0,0,0,0},{0,0,0,0},{0,0,0,0},{0,0,0,0}};

        for (int kc = 0; kc < 3; kc++) {
#pragma unroll
            for (int r2 = 0; r2 < 2; r2++) {
                int idx = tid + r2 * 256;
                int m = idx >> 3, kq = idx & 7;
                size_t ao = (size_t)(bm + m) * CC + kc * 64 + kq * 8;
                *(short8*)&Ah[m * 72 + kq * 8] = *(const short8*)(xh16 + ao);
                size_t bo = (size_t)(bn + m) * 192 + kc * 64 + kq * 8;
                *(short8*)&Bh[m * 72 + kq * 8] = *(const short8*)(wh16 + bo);
            }
            __syncthreads();
            int n0 = wv * 16;
            int k8 = lane >> 4;
            int col = lane & 15;
#pragma unroll
            for (int ks = 0; ks < 64; ks += 32) {
                int koff = ks + k8 * 8;
                half8 bf = *(const half8*)&Bh[(n0 + col) * 72 + koff];
#pragma unroll
                for (int fm = 0; fm < 4; fm++) {
                    half8 af = *(const half8*)&Ah[(fm * 16 + col) * 72 + koff];
                    acc[fm] = __builtin_amdgcn_mfma_f32_16x16x32_f16(af, bf, acc[fm], 0, 0, 0);
                }
            }
            __syncthreads();
        }
        // LDS transpose: Ds[m][n], stride 68
        {
            int col = lane & 15, rowq = lane >> 4;
#pragma unroll
            for (int fm = 0; fm < 4; fm++)
#pragma unroll
                for (int rg = 0; rg < 4; rg++)
                    Ds[(fm * 16 + rowq * 4 + rg) * 68 + wv * 16 + col] = acc[fm][rg];
        }
        __syncthreads();
        // Store slab-native: dst[((cc8*4+b)*4+r)*6272 + t*448 + w*8 + ci]
        {
            int c4 = tid & 15, m0 = tid >> 4;
            int cg = bn + c4 * 4;
            float* dst = (cg < 192) ? u : z;
            int cc = (cg < 192) ? cg : cg - 192;
            int cc8 = cc >> 3, ci = cc & 7;           // ci in {0,4}
            size_t cbase = (size_t)cc8 * 100352;      // 4b*4r*14t*448
#pragma unroll
            for (int p = 0; p < 4; p++) {
                int m = m0 + p * 16;
                int gp = bm + m;
                int b = gp / HWW, pp = gp - b * HWW;
                int hh = pp / 56, ww2 = pp - hh * 56;
                int rr = hh & 3, tt2 = hh >> 2;
                size_t off = cbase + ((size_t)((b * 4 + rr) * 14 + tt2)) * 448 + ww2 * 8 + ci;
                float4 v = *(float4*)&Ds[m * 68 + c4 * 4];
                *(float4*)&dst[off] = v;
            }
        }
    }
}

// ---------------------------------------------------------------------------
// Kernel 3: fused softmax + H+W accumulation + bias + BN + GELU.
// Block = (b, r, cc8, th). Slab-native u/z; inline per-pixel softmax -> W16
// LDS (stride 36 shorts, bank-spread); weights consumed as ds_read_b64
// (4 f16 weights per LDS op -> 7 reads/pixel instead of 14).
// Grid 768 = 4b x 4r x 24cc x 2th, 448 threads (tid = w*8+c).
// ---------------------------------------------------------------------------
__global__ __launch_bounds__(448, 1) void k_tail(const float* __restrict__ u,
                                                 const float* __restrict__ z,
                                                 const float* __restrict__ sp,
                                                 const float* __restrict__ cb,
                                                 const float* __restrict__ gma,
                                                 const float* __restrict__ bta,
                                                 const float* __restrict__ mea,
                                                 const float* __restrict__ var,
                                                 float* __restrict__ y) {
    __shared__ __align__(16) char arena[25088 + 28224];       // 53312 B
    float* Zs = (float*)arena;                                // [t][w][c] 25088B
    unsigned short* W16 = (unsigned short*)(arena + 25088);   // [pixl][36] 28224B
    float* Ys = (float*)(arena + 25088);                      // 7*448 f, aliased

    int tid = threadIdx.x, bid = blockIdx.x;
    int th = bid & 1;
    int t1 = bid >> 1;                    // 0..383
    int cc = t1 % 24;
    int t2 = t1 / 24;                     // 0..15
    int r = t2 & 3;
    int b = t2 >> 2;
    int w = tid >> 3, c = tid & 7;
    int cg = cc * 8 + c;
    int hbase = r + 4 * (th * 7);

    size_t slab = ((size_t)cc * BB + b) * 4 + r;
    const float* zg = z + slab * 6272;
    const float* ug = u + slab * 6272;

    // (1) issue slab loads early (contiguous, fully coalesced); write LDS late
    float4 zva0 = *(const float4*)(zg + tid * 8);
    float4 zva1 = *(const float4*)(zg + tid * 8 + 4);
    float4 zvb0, zvb1;
    if (tid < 336) {
        zvb0 = *(const float4*)(zg + (tid + 448) * 8);
        zvb1 = *(const float4*)(zg + (tid + 448) * 8 + 4);
    }
    float acc0[7];
#pragma unroll
    for (int tt = 0; tt < 7; tt++)
        acc0[tt] = ug[(th * 7 + tt) * 448 + tid];

    // (2) softmax: one pixel per thread (392 pixels), weights -> W16 LDS
    if (tid < 392) {
        int tq = tid / 56, ww = tid - tq * 56;
        int row = hbase + 4 * tq;
        size_t gp = (size_t)b * HWW + row * WW + ww;
        const float4* p0 = (const float4*)&sp[gp * 32];
        const float4* p1 = (const float4*)&sp[((size_t)(4 * HWW) + gp) * 32];
        float sc[28];
#pragma unroll
        for (int j = 0; j < 7; j++) {
            float4 a4 = p0[j], v4 = p1[j];
            sc[4 * j + 0] = a4.x + v4.x; sc[4 * j + 1] = a4.y + v4.y;
            sc[4 * j + 2] = a4.z + v4.z; sc[4 * j + 3] = a4.w + v4.w;
        }
        float mx = -1e30f;
#pragma unroll
        for (int s = 0; s < 27; s++) mx = fmaxf(mx, sc[s]);
        float sum = 0.f;
#pragma unroll
        for (int s = 0; s < 27; s++) { sc[s] = __expf(sc[s] - mx); sum += sc[s]; }
        float inv = __builtin_amdgcn_rcpf(sum);
        unsigned short hw[28];
#pragma unroll
        for (int s = 0; s < 27; s++) hw[s] = f2h(sc[s] * inv);
        hw[27] = 0;
        unsigned short* d = &W16[tid * 36];
        *(short8*)(d)      = *(short8*)&hw[0];
        *(short8*)(d + 8)  = *(short8*)&hw[8];
        *(short8*)(d + 16) = *(short8*)&hw[16];
        *(short4v*)(d + 24) = *(short4v*)&hw[24];
    }

    // (3) write z registers to LDS (layout identical to global slab), barrier
    {
        float* dst = &Zs[tid * 8];
        *(float4*)dst = zva0;
        *(float4*)(dst + 4) = zva1;
    }
    if (tid < 336) {
        float* dst = &Zs[(tid + 448) * 8];
        *(float4*)dst = zvb0;
        *(float4*)(dst + 4) = zvb1;
    }
    __syncthreads();

    // (4) compute
    float zc[14];
#pragma unroll
    for (int m = 0; m < 14; m++) {
        int t0 = m + th * 7;
        if (t0 >= 14) t0 -= 14;
        zc[m] = Zs[(t0 * 56 + w) * 8 + c];
    }

    float bias = cb[cg];
    float ginv = gma[cg] * rsqrtf(var[cg] + 1e-5f);
    float bt = bta[cg];
    float me = mea[cg];

    float vout[7];
#pragma unroll
    for (int tt = 0; tt < 7; tt++) {
        int t = th * 7 + tt;
        int pb = (tt * 56 + w) * 36;
        // 7 x ds_read_b64 -> 28 f16 weights (halves 0..27; 27 is the 0 pad)
        const uint2* wp = (const uint2*)&W16[pb];
        float wt[28];
#pragma unroll
        for (int j = 0; j < 7; j++) {
            uint2 rr2 = wp[j];
            float2 fa = h2f2(rr2.x), fb = h2f2(rr2.y);
            wt[4 * j + 0] = fa.x; wt[4 * j + 1] = fa.y;
            wt[4 * j + 2] = fb.x; wt[4 * j + 3] = fb.y;
        }
        float a = acc0[tt];
        // H-part: wt[i] * z(row tt-i), zc rotated so indices are static
#pragma unroll
        for (int i = 0; i < 14; i++)
            a += wt[i] * zc[(tt - i + 28) % 14];
        // W-part: wt[13+j] * z(col w-4j), from LDS
#pragma unroll
        for (int j = 1; j <= 13; j++) {
            int wj = w - 4 * j; if (wj < 0) wj += 56;
            a += wt[13 + j] * Zs[(t * 56 + wj) * 8 + c];
        }
        float v = (a + bias - me) * ginv + bt;
        vout[tt] = 0.5f * v * (1.0f + erff(v * 0.70710678118654752f));
    }

    // (5) output restage: Ys aliases W16 (compute done), coalesced y stores
    __syncthreads();
#pragma unroll
    for (int tt = 0; tt < 7; tt++)
        Ys[tt * 448 + c * 56 + w] = vout[tt];
    __syncthreads();
    {
        int c_out = tid / 56, w_out = tid - c_out * 56;
        size_t ybase = ((size_t)(b * CC + cc * 8 + c_out)) * HWW + w_out;
#pragma unroll
        for (int tt = 0; tt < 7; tt++)
            y[ybase + (size_t)(hbase + 4 * tt) * 56] = Ys[tt * 448 + c_out * 56 + w_out];
    }
}

// ---------------------------------------------------------------------------
extern "C" void kernel_launch(void* const* d_in, const int* in_sizes, int n_in,
                              void* d_out, int out_size, void* d_ws, size_t ws_size,
                              hipStream_t stream) {
    const float* x   = (const float*)d_in[0];
    const float* cw  = (const float*)d_in[1];
    const float* cb  = (const float*)d_in[2];
    const float* gma = (const float*)d_in[3];
    const float* bta = (const float*)d_in[4];
    const float* mea = (const float*)d_in[5];
    const float* var = (const float*)d_in[6];
    float* out = (float*)d_out;

    float* ws = (float*)d_ws;
    float*          sp   = ws;                                  //   802,816 f
    float*          u    = ws + 802816;                         // 2,408,448 f (slab-native)
    float*          z    = ws + 3211264;                        // 2,408,448 f (slab-native)
    unsigned short* xh16 = (unsigned short*)(ws + 5619712);     // 2,408,448 us -> ends 6,823,936
    unsigned short* wh16 = (unsigned short*)(ws + 6823936);     //    73,728 us

    k_pre<<<2640, 256, 0, stream>>>(x, cw, xh16, wh16);
    k_mid<<<2968, 256, 0, stream>>>(xh16, wh16, sp, u, z);
    k_tail<<<768, 448, 0, stream>>>(u, z, sp, cb, gma, bta, mea, var, out);
}